// Round 19
// baseline (255.744 us; speedup 1.0000x reference)
//
#include <hip/hip_runtime.h>

// ---------------------------------------------------------------------------
// SimVP Decoder, round 19: R18 + packed PixelShuffle stores.
// Old PSF epilogue: 8x 2-byte scatter stores per lane per s (stride-4B,
// quarter-density). Algebra: for fixed (s,sub), j=0..3 are exactly the
// (rr,ss) = (0,0),(0,1),(1,0),(1,1) quad of ONE plane c -> pack into 2
// coalesced u32 stores (top row {a0,a1}, bottom row {a2,a3}); consecutive
// lanes write consecutive 4B words. Conv2's 52MB write becomes full-density.
// Everything else byte-identical to R18/R17 (passed, absmax 0.0078):
//   pad(hid)->hidP ; conv0+PS -> A(bf16 NCHW) ; act1 -> Ap(NHWC) ; conv1 ->
//   Bb ; act2 -> Bp ; conv2+PS -> Cb ; act3(+enc1) -> Cp ; conv3 -> Db ;
//   readout -> Y ; feamap ; nz ; final.  R8 slot-spread stats throughout.
// ---------------------------------------------------------------------------

#define DEVFN static __device__ __forceinline__

typedef short v8s __attribute__((ext_vector_type(8)));
typedef float v4f __attribute__((ext_vector_type(4)));

DEVFN float silu_f(float t) { return t / (1.f + __expf(-t)); }

DEVFN ushort f2bf(float x) {
  union { float f; unsigned u; } t; t.f = x;
  unsigned r = t.u + 0x7FFFu + ((t.u >> 16) & 1u);
  return (ushort)(r >> 16);
}

DEVFN float bf2f(unsigned u) {
  union { unsigned i; float f; } t; t.i = u << 16; return t.f;
}

DEVFN float ldf(float x) { return x; }
DEVFN float ldf(ushort u) { return bf2f(u); }

__global__ void zero_k(float* __restrict__ p, int n) {
  int i = blockIdx.x * 256 + threadIdx.x;
  if (i < n) p[i] = 0.f;
}

// ---- weight repack: [OC][64][3][3] f32 -> bf16 [kc=tap*8+ic/8][OC][8] -----
template<int OC>
__global__ void repackw_k(const float* __restrict__ src, ushort* __restrict__ dst) {
  int i = blockIdx.x * 256 + threadIdx.x;
  if (i >= OC * 576) return;
  int oc = i / 576, r = i - oc * 576;      // r = ic*9 + tap
  int ic = r / 9, tap = r - ic * 9;
  int kc = tap * 8 + (ic >> 3), j = ic & 7;
  dst[((size_t)kc * OC + oc) * 8 + j] = f2bf(src[i]);
}

// ---- zero the 1-px border of a padded NHWC bf16 buffer --------------------
template<int HP, int WP>
__global__ void border_k(ushort* __restrict__ outP) {
  int idx = blockIdx.x * 256 + threadIdx.x;
  if (idx >= 16 * HP * WP) return;
  int p = idx % (HP * WP);
  int y = p / WP, x = p - y * WP;
  if (y == 0 || y == HP - 1 || x == 0 || x == WP - 1) {
    uint4 z = {0u, 0u, 0u, 0u};
    uint4* dst = (uint4*)(outP + (size_t)idx * 64);
    #pragma unroll
    for (int k = 0; k < 8; ++k) dst[k] = z;
  }
}

// ---- slot-summed GN stats -> (mean, rstd) ---------------------------------
DEVFN void gn_stats(const float* __restrict__ st, int bg, float N,
                    float& mean, float& rstd) {
  float s = 0.f, q = 0.f;
  #pragma unroll
  for (int sl = 0; sl < 8; ++sl) {
    s += st[sl * 64 + bg * 2 + 0];
    q += st[sl * 64 + bg * 2 + 1];
  }
  float m = s / N;
  mean = m;
  rstd = rsqrtf(q / N - m * m + 1e-5f);
}

// ---- act: NCHW (f32 or bf16) -> padded NHWC bf16 via swizzled LDS ---------
// MODE: 0 copy (pad only); 1 GN+SiLU; 2 GN+SiLU + addsrc(f32)
template<int HW_TOT, int WOUT, int MODE, typename T>
__global__ __launch_bounds__(256)
void act_k(const T* __restrict__ in, const float* __restrict__ st,
           const float* __restrict__ gw, const float* __restrict__ gb,
           const float* __restrict__ addsrc, ushort* __restrict__ outP)
{
  constexpr int HOUT = HW_TOT / WOUT;
  constexpr int WP = WOUT + 2, HP = HOUT + 2;
  __shared__ uint4 sT[256 * 8];            // [pixel][slot], slot = cc ^ (pix&7)
  const int tid = threadIdx.x;
  constexpr int NBLK = (HW_TOT + 255) / 256;
  const int b  = blockIdx.x / NBLK;
  const int p0 = (blockIdx.x - b * NBLK) * 256;
  const int px = p0 + tid;

  float mean[2], rstd[2];
  if (MODE >= 1) {
    const float N = 32.f * HW_TOT;
    #pragma unroll
    for (int g = 0; g < 2; ++g) gn_stats(st, b * 2 + g, N, mean[g], rstd[g]);
  }
  if (px < HW_TOT) {
    const T* ip = in + (size_t)b * 64 * HW_TOT + px;
    #pragma unroll 2
    for (int cc = 0; cc < 8; ++cc) {
      unsigned w[4];
      #pragma unroll
      for (int jp = 0; jp < 4; ++jp) {
        float v0, v1;
        #pragma unroll
        for (int h = 0; h < 2; ++h) {
          int c = cc * 8 + jp * 2 + h;
          float v = ldf(ip[(size_t)c * HW_TOT]);
          if (MODE >= 1) {
            v = silu_f((v - mean[c >> 5]) * rstd[c >> 5] * gw[c] + gb[c]);
            if (MODE == 2) v += addsrc[(size_t)(b * 64 + c) * HW_TOT + px];
          }
          if (h == 0) v0 = v; else v1 = v;
        }
        w[jp] = (unsigned)f2bf(v0) | ((unsigned)f2bf(v1) << 16);
      }
      uint4 pk = {w[0], w[1], w[2], w[3]};
      sT[tid * 8 + (cc ^ (tid & 7))] = pk;
    }
  }
  __syncthreads();
  const int o = tid & 7, pr = tid >> 3;
  #pragma unroll
  for (int i = 0; i < 8; ++i) {
    int p = i * 32 + pr;
    int gpx = p0 + p;
    if (gpx < HW_TOT) {
      int y = gpx / WOUT, x = gpx - y * WOUT;
      uint4 val = sT[p * 8 + (o ^ (p & 7))];
      *(uint4*)(outP + (((size_t)(b * HP) + y + 1) * WP + (x + 1)) * 64 + o * 8) = val;
    }
  }
}

// ---- MFMA implicit-GEMM 3x3 conv, single-staged row strip -----------------
// In: padded NHWC bf16. Out: bf16 NCHW, PRE-NORM (stats fused, f32 accs).
// PSF epilogue: lane owns the full 2x2 quad of one plane -> 2 packed u32
// stores (coalesced) instead of 8x 2B scatter.

#define FE18(M) M(0) M(1) M(2) M(3) M(4) M(5) M(6) M(7) M(8) M(9) M(10) \
                M(11) M(12) M(13) M(14) M(15) M(16) M(17)

#define WDL(t) \
  v8s Wa##t = ((const v8s*)wrep)[(size_t)((t) * 4 + sub) * OCT + ocbase + lx]; \
  v8s Wb##t = ((const v8s*)wrep)[(size_t)((t) * 4 + sub) * OCT + ocbase + 16 + lx];

// step t: tap = t>>1 (dy=t/6, dx=(t>>1)%3), icc-half = t&1
#define KST(t) { \
    const int col_ = lx + (((t) >> 1) % 3); \
    v8s b_ = __builtin_bit_cast(v8s, sQ[((rbase + wrow + (t) / 6) * LWS + xb + col_) * 8 + \
                                        (((((t) & 1) * 4 + sub)) ^ ((xb + col_) & 7))]); \
    a0 = __builtin_amdgcn_mfma_f32_16x16x32_bf16(Wa##t, b_, a0, 0, 0, 0); \
    a1 = __builtin_amdgcn_mfma_f32_16x16x32_bf16(Wb##t, b_, a1, 0, 0, 0); }

template<int HIN, int WIN, int WT, int NG, int RPB, int OCT, bool PSF,
         int WEU_MIN, int WEU_MAX>
__global__
__attribute__((amdgpu_flat_work_group_size(256, 256),
               amdgpu_waves_per_eu(WEU_MIN, WEU_MAX)))
void convm_k(const uint4* __restrict__ inP, const ushort* __restrict__ wrep,
             const float* __restrict__ bias, ushort* __restrict__ out,
             float* __restrict__ stp)
{
  constexpr int HP = HIN + 2, WP = WIN + 2;
  constexpr int LH = RPB + 2, LW = WT + 2;
  constexpr int NOCB = OCT / 64;
  constexpr int LRD = (NG * 16 + 2 > LW) ? (NG * 16 + 2) : LW;
  constexpr int LWS = (LRD + 7) & ~7;      // multiple of 8: (pix&7)==(col&7)
  constexpr int NCHUNK = LH * LWS * 8;
  static_assert(NCHUNK % 256 == 0, "staging must tile evenly");
  constexpr int STK = NCHUNK / 256;
  __shared__ uint4 sQ[NCHUNK];
  __shared__ float red[4][2];

  const int tid  = threadIdx.x;
  const int lane = tid & 63;
  const int wave = tid >> 6;
  const int sub  = lane >> 4;
  const int lx   = lane & 15;
  const int wrow = wave >> 1;              // row within pair
  const int b    = blockIdx.y / NOCB;
  const int ocb  = blockIdx.y - b * NOCB;
  constexpr int NTX = WIN / WT;
  const int tx    = blockIdx.x % NTX;
  const int ych   = blockIdx.x / NTX;
  const int x0    = tx * WT;
  const int ybase = ych * RPB;
  const int ocbase = ocb * 64 + (wave & 1) * 32;

  // ---- staging FIRST: batched loads -> LDS (staging regs die here) -------
  const uint4* gbase = inP + ((size_t)(b * HP + ybase) * WP + x0) * 8;
  {
    uint4 stg[STK];
    #pragma unroll
    for (int k = 0; k < STK; ++k) {
      int q = tid + k * 256;
      int p = q >> 3, cc = q & 7;
      int r = p / LWS, cx = p - r * LWS;
      stg[k] = gbase[((size_t)r * WP + cx) * 8 + cc];
    }
    #pragma unroll
    for (int k = 0; k < STK; ++k) {
      int q = tid + k * 256;
      int p = q >> 3, cc = q & 7;
      int cx = p - (p / LWS) * LWS;
      sQ[p * 8 + (cc ^ (cx & 7))] = stg[k];
    }
  }

  // ---- weights AFTER staging (overlap LDS-write drain, pre-barrier) ------
  FE18(WDL)

  const v4f bi0 = *(const v4f*)&bias[ocbase + sub * 4];
  const v4f bi1 = *(const v4f*)&bias[ocbase + 16 + sub * 4];

  __syncthreads();

  float sA = 0.f, qA = 0.f;

  for (int it = 0; it < RPB / 2; ++it) {
    const int rbase = it * 2;
    const int y = ybase + rbase + wrow;
    for (int xg = 0; xg < NG; ++xg) {
      const int xb = xg * 16;
      v4f a0 = bi0, a1 = bi1;
      FE18(KST)
      const int x = x0 + xb + lx;
      if ((NG * 16 == WT) || (x < WIN)) {
        #pragma unroll
        for (int s = 0; s < 2; ++s) {
          const v4f a = s ? a1 : a0;
          if (!PSF) {
            #pragma unroll
            for (int j = 0; j < 4; ++j) {
              int oc = ocbase + s * 16 + sub * 4 + j;
              out[((size_t)(b * OCT + oc) * HIN + y) * WIN + x] = f2bf(a[j]);
            }
          } else {
            // lane owns the full 2x2 quad of plane c:
            // j=0->(0,0) j=1->(0,1) j=2->(1,0) j=3->(1,1)
            const int c = (ocbase + s * 16 + sub * 4) >> 2;
            unsigned top = (unsigned)f2bf(a[0]) | ((unsigned)f2bf(a[1]) << 16);
            unsigned bot = (unsigned)f2bf(a[2]) | ((unsigned)f2bf(a[3]) << 16);
            const size_t qb =
              ((size_t)(b * 64 + c) * (2 * HIN) + 2 * y) * (2 * WIN) + 2 * x;
            *(unsigned*)(out + qb) = top;
            *(unsigned*)(out + qb + 2 * WIN) = bot;
          }
          #pragma unroll
          for (int j = 0; j < 4; ++j) { sA += a[j]; qA += a[j] * a[j]; }
        }
      }
    }
  }

  // GroupNorm stats (f32 accumulators, exact)
  #pragma unroll
  for (int o = 32; o >= 1; o >>= 1) {
    sA += __shfl_down(sA, o);
    qA += __shfl_down(qA, o);
  }
  if (lane == 0) { red[wave][0] = sA; red[wave][1] = qA; }
  __syncthreads();
  if (tid == 0) {
    float* basep = stp + ((blockIdx.x ^ blockIdx.y) & 7) * 64;
    if (PSF) {
      int g = ocb >> 1;
      atomicAdd(&basep[(b * 2 + g) * 2 + 0],
                red[0][0] + red[1][0] + red[2][0] + red[3][0]);
      atomicAdd(&basep[(b * 2 + g) * 2 + 1],
                red[0][1] + red[1][1] + red[2][1] + red[3][1]);
    } else {
      atomicAdd(&basep[(b * 2 + 0) * 2 + 0], red[0][0] + red[2][0]);
      atomicAdd(&basep[(b * 2 + 0) * 2 + 1], red[0][1] + red[2][1]);
      atomicAdd(&basep[(b * 2 + 1) * 2 + 0], red[1][0] + red[3][0]);
      atomicAdd(&basep[(b * 2 + 1) * 2 + 1], red[1][1] + red[3][1]);
    }
  }
}

// ---- readout: Y[b,o,pix] = rb[o] + sum_c GN_SiLU(D)[b,c,pix] * rw[o,c] ----
__global__ __launch_bounds__(256)
void readout_k(const ushort* __restrict__ D, const float* __restrict__ st,
               const float* __restrict__ gw, const float* __restrict__ gb,
               const float* __restrict__ rw, const float* __restrict__ rb,
               float* __restrict__ Y)
{
  int idx = blockIdx.x * 256 + threadIdx.x;
  if (idx >= 16 * 25600) return;
  int b = idx / 25600, pix = idx - b * 25600;
  const float N = 32.f * 25600.f;
  float mean[2], rstd[2];
  #pragma unroll
  for (int g = 0; g < 2; ++g) gn_stats(st, b * 2 + g, N, mean[g], rstd[g]);
  float a0 = rb[0], a1 = rb[1], a2 = rb[2];
  const ushort* dp = D + (size_t)(b * 64) * 25600 + pix;
  #pragma unroll 4
  for (int c = 0; c < 64; ++c) {
    float x = bf2f(dp[(size_t)c * 25600]);
    float t = (x - mean[c >> 5]) * rstd[c >> 5] * gw[c] + gb[c];
    float v = silu_f(t);
    a0 = fmaf(v, rw[c], a0);
    a1 = fmaf(v, rw[64 + c], a1);
    a2 = fmaf(v, rw[128 + c], a2);
  }
  Y[(size_t)(b * 3 + 0) * 25600 + pix] = a0;
  Y[(size_t)(b * 3 + 1) * 25600 + pix] = a1;
  Y[(size_t)(b * 3 + 2) * 25600 + pix] = a2;
}

// ---- feamap: argx = conv(Y, fw, stride 4)/16, first 3 channels ------------
__global__ void feamap_k(const float* __restrict__ Y, const float* __restrict__ fw,
                         float* __restrict__ argx)
{
  int idx = blockIdx.x * 256 + threadIdx.x;
  if (idx >= 16 * 3 * 1600) return;
  int b  = idx / (3 * 1600);
  int o  = (idx / 1600) % 3;
  int ij = idx % 1600;
  int i = ij / 40, j = ij - i * 40;
  float s = 0.f;
  #pragma unroll
  for (int c = 0; c < 3; ++c)
    #pragma unroll
    for (int u = 0; u < 4; ++u)
      #pragma unroll
      for (int v = 0; v < 4; ++v)
        s += Y[((size_t)(b * 3 + c) * 160 + (4 * i + u)) * 160 + (4 * j + v)]
             * fw[((o * 3 + c) * 4 + u) * 4 + v];
  argx[idx] = s * (1.f / 16.f);
}

__global__ void nz_k(const float* __restrict__ attn, float* __restrict__ nzinv) {
  int idx = blockIdx.x * 256 + threadIdx.x;
  if (idx >= 16 * 3 * 256) return;
  const float* p = attn + (size_t)idx * 16;
  int c = 0;
  #pragma unroll
  for (int k = 0; k < 16; ++k) c += (p[k] != 0.f);
  nzinv[idx] = 1.f / ((float)c + 1e-5f);
}

__global__ void final_k(const float* __restrict__ Y, const float* __restrict__ attn,
                        const float* __restrict__ nzinv, const float* __restrict__ argx,
                        float* __restrict__ out)
{
  int idx = blockIdx.x * 256 + threadIdx.x;
  if (idx >= 16 * 3 * 25600) return;
  int bc  = idx / 25600;
  int pix = idx - bc * 25600;
  int y = pix / 160, x = pix - y * 160;
  int l  = (y / 10) * 16 + (x / 10);
  int pi = y % 10,  pj = x % 10;
  const float* ar = attn + ((size_t)bc * 256 + l) * 16;
  const float* ax = argx + (size_t)bc * 1600;
  float inv = nzinv[bc * 256 + l];
  float corr = 0.f;
  #pragma unroll
  for (int k = 0; k < 16; ++k)
    corr += ar[k] * ax[((k >> 2) * 10 + pi) * 40 + ((k & 3) * 10 + pj)];
  float yv = Y[idx];
  out[idx] = yv * (1.f + corr * inv);
}

// ---------------------------------------------------------------------------
extern "C" void kernel_launch(void* const* d_in, const int* in_sizes, int n_in,
                              void* d_out, int out_size, void* d_ws, size_t ws_size,
                              hipStream_t stream)
{
  const float* attn = (const float*)d_in[0];
  const float* hid  = (const float*)d_in[1];
  const float* enc1 = (const float*)d_in[2];
  const float* d0w  = (const float*)d_in[3];
  const float* d0b  = (const float*)d_in[4];
  const float* d0gw = (const float*)d_in[5];
  const float* d0gb = (const float*)d_in[6];
  const float* d1w  = (const float*)d_in[7];
  const float* d1b  = (const float*)d_in[8];
  const float* d1gw = (const float*)d_in[9];
  const float* d1gb = (const float*)d_in[10];
  const float* d2w  = (const float*)d_in[11];
  const float* d2b  = (const float*)d_in[12];
  const float* d2gw = (const float*)d_in[13];
  const float* d2gb = (const float*)d_in[14];
  const float* d3w  = (const float*)d_in[15];
  const float* d3b  = (const float*)d_in[16];
  const float* d3gw = (const float*)d_in[17];
  const float* d3gb = (const float*)d_in[18];
  const float* rw   = (const float*)d_in[19];
  const float* rb   = (const float*)d_in[20];
  const float* fw   = (const float*)d_in[21];

  float* ws = (float*)d_ws;
  size_t o = 0;
  float* bufA  = ws + o; o += (size_t)16 * 64 * 80 * 80;       // A/Bb (bf16) + Y/argx/nzv (f32)
  float* bufAp = ws + o; o += (size_t)16 * 82 * 82 * 64 / 2;   // Ap / Bp  (NHWC bf16)
  float* bufC  = ws + o; o += (size_t)16 * 64 * 160 * 160 / 2; // Cb / Db (NCHW bf16)
  float* bufCp = ws + o; o += (size_t)16 * 162 * 162 * 64 / 2; // Cp (NHWC bf16)
  float* hidPf = ws + o; o += (size_t)16 * 42 * 42 * 64 / 2;   // hidP
  float* st    = ws + o; o += 4 * 512;                         // slotted stats
  float* w0f   = ws + o; o += (size_t)72 * 256 * 8 / 2;
  float* w1f   = ws + o; o += (size_t)72 * 64 * 8 / 2;
  float* w2f   = ws + o; o += (size_t)72 * 256 * 8 / 2;
  float* w3f   = ws + o; o += (size_t)72 * 64 * 8 / 2;

  ushort* A    = (ushort*)bufA;            // bf16 NCHW [16,64,80,80]
  ushort* Bb   = (ushort*)bufA;            // aliases A (A dead after act1)
  ushort* Ap   = (ushort*)bufAp;
  ushort* Bp   = (ushort*)bufAp;
  ushort* Cb   = (ushort*)bufC;
  ushort* Db   = (ushort*)bufC;
  ushort* Cp   = (ushort*)bufCp;
  ushort* hidP = (ushort*)hidPf;
  float*  Y    = bufA;                     // Bb dead after act2
  float*  argx = bufA + (size_t)16 * 3 * 25600;
  float*  nzv  = argx + (size_t)16 * 3 * 1600;
  ushort* wr0  = (ushort*)w0f;
  ushort* wr1  = (ushort*)w1f;
  ushort* wr2  = (ushort*)w2f;
  ushort* wr3  = (ushort*)w3f;

  zero_k<<<8, 256, 0, stream>>>(st, 4 * 512);

  repackw_k<256><<<(256 * 576 + 255) / 256, 256, 0, stream>>>(d0w, wr0);
  repackw_k<64><<<(64 * 576 + 255) / 256, 256, 0, stream>>>(d1w, wr1);
  repackw_k<256><<<(256 * 576 + 255) / 256, 256, 0, stream>>>(d2w, wr2);
  repackw_k<64><<<(64 * 576 + 255) / 256, 256, 0, stream>>>(d3w, wr3);

  // borders (zeroed every call; act kernels write interiors only)
  border_k<42, 42><<<(16 * 42 * 42 + 255) / 256, 256, 0, stream>>>(hidP);
  border_k<82, 82><<<(16 * 82 * 82 + 255) / 256, 256, 0, stream>>>(Ap);
  border_k<162, 162><<<(16 * 162 * 162 + 255) / 256, 256, 0, stream>>>(Cp);

  // pad hid -> hidP (NHWC bf16)
  act_k<1600, 40, 0, float><<<16 * 7, 256, 0, stream>>>(
      hid, nullptr, nullptr, nullptr, nullptr, hidP);

  // stage 0: conv(hidP)+PS -> A (bf16 NCHW, pre-norm), stats st0
  convm_k<40, 40, 40, 3, 10, 256, true, 1, 1>
    <<<dim3(4, 16 * 4), 256, 0, stream>>>((const uint4*)hidP, wr0, d0b, A,
                                          st + 0 * 512);

  // act1: GN+SiLU(A) -> Ap (NHWC)
  act_k<6400, 80, 1, ushort><<<16 * 25, 256, 0, stream>>>(
      A, st + 0 * 512, d0gw, d0gb, nullptr, Ap);

  // stage 1: conv(Ap) -> Bb, stats st1
  convm_k<80, 80, 16, 1, 10, 64, false, 2, 8>
    <<<dim3(40, 16), 256, 0, stream>>>((const uint4*)Ap, wr1, d1b, Bb,
                                       st + 1 * 512);

  // act2: GN+SiLU(Bb) -> Bp
  act_k<6400, 80, 1, ushort><<<16 * 25, 256, 0, stream>>>(
      Bb, st + 1 * 512, d1gw, d1gb, nullptr, Bp);

  // stage 2: conv(Bp)+PS -> Cb, stats st2
  convm_k<80, 80, 16, 1, 10, 256, true, 2, 8>
    <<<dim3(40, 16 * 4), 256, 0, stream>>>((const uint4*)Bp, wr2, d2b, Cb,
                                           st + 2 * 512);

  // act3: GN+SiLU(Cb) + enc1 -> Cp
  act_k<25600, 160, 2, ushort><<<16 * 100, 256, 0, stream>>>(
      Cb, st + 2 * 512, d2gw, d2gb, enc1, Cp);

  // stage 3: conv(Cp) -> Db, stats st3
  convm_k<160, 160, 16, 1, 10, 64, false, 2, 8>
    <<<dim3(160, 16), 256, 0, stream>>>((const uint4*)Cp, wr3, d3b, Db,
                                        st + 3 * 512);

  // readout: Y = 1x1conv(GN_SiLU(Db))
  readout_k<<<(16 * 25600 + 255) / 256, 256, 0, stream>>>(Db, st + 3 * 512,
      d3gw, d3gb, rw, rb, Y);

  feamap_k<<<(16 * 3 * 1600 + 255) / 256, 256, 0, stream>>>(Y, fw, argx);
  nz_k<<<(16 * 3 * 256 + 255) / 256, 256, 0, stream>>>(attn, nzv);
  final_k<<<(16 * 3 * 25600 + 255) / 256, 256, 0, stream>>>(Y, attn, nzv, argx,
      (float*)d_out);
}

// Round 20
// 244.582 us; speedup vs baseline: 1.0456x; 1.0456x over previous
//
#include <hip/hip_runtime.h>

// ---------------------------------------------------------------------------
// SimVP Decoder, round 20: R19 + launch-count reduction + readout vectorize.
//   1) zero + 4x repack fused into prep_k; 3x border fused into border3_k
//      (20 -> 14 kernel launches, ~12us of dispatch gaps removed).
//   2) nz_k DELETED: final_k counts nonzeros inline from the same attn row
//      it already reads for the einsum (zero extra traffic).
//   3) readout_k: 2 pixels/thread, u32 (bf16x2) channel-plane loads ->
//      full-density wave loads; 6 acc chains.
// Convs/acts byte-identical to R19/R17 lineage (passed, absmax 0.0078):
//   pad(hid)->hidP ; conv0+PS -> A(bf16 NCHW) ; act1 -> Ap(NHWC) ; conv1 ->
//   Bb ; act2 -> Bp ; conv2+PS -> Cb ; act3(+enc1) -> Cp ; conv3 -> Db ;
//   readout -> Y ; feamap ; final.  R8 slot-spread stats throughout.
// ---------------------------------------------------------------------------

#define DEVFN static __device__ __forceinline__

typedef short v8s __attribute__((ext_vector_type(8)));
typedef float v4f __attribute__((ext_vector_type(4)));

DEVFN float silu_f(float t) { return t / (1.f + __expf(-t)); }

DEVFN ushort f2bf(float x) {
  union { float f; unsigned u; } t; t.f = x;
  unsigned r = t.u + 0x7FFFu + ((t.u >> 16) & 1u);
  return (ushort)(r >> 16);
}

DEVFN float bf2f(unsigned u) {
  union { unsigned i; float f; } t; t.i = u << 16; return t.f;
}

DEVFN float ldf(float x) { return x; }
DEVFN float ldf(ushort u) { return bf2f(u); }

// ---- fused prep: zero stats + repack all 4 weight tensors -----------------
DEVFN void repack1(const float* __restrict__ src, ushort* __restrict__ dst,
                   int i, int OC) {
  int oc = i / 576, r = i - oc * 576;      // r = ic*9 + tap
  int ic = r / 9, tap = r - ic * 9;
  int kc = tap * 8 + (ic >> 3), j = ic & 7;
  dst[((size_t)kc * OC + oc) * 8 + j] = f2bf(src[i]);
}

__global__ __launch_bounds__(256)
void prep_k(const float* __restrict__ s0, const float* __restrict__ s1,
            const float* __restrict__ s2, const float* __restrict__ s3,
            ushort* __restrict__ d0, ushort* __restrict__ d1,
            ushort* __restrict__ d2, ushort* __restrict__ d3,
            float* __restrict__ st)
{
  int i = blockIdx.x * 256 + threadIdx.x;
  if (i < 2048) st[i] = 0.f;
  int j = i;
  if (j < 147456) { repack1(s0, d0, j, 256); return; }
  j -= 147456;
  if (j < 36864)  { repack1(s1, d1, j, 64);  return; }
  j -= 36864;
  if (j < 147456) { repack1(s2, d2, j, 256); return; }
  j -= 147456;
  if (j < 36864)  { repack1(s3, d3, j, 64);  return; }
}

// ---- fused border zeroing for the 3 padded NHWC buffers -------------------
__global__ __launch_bounds__(256)
void border3_k(ushort* __restrict__ hidP, ushort* __restrict__ Ap,
               ushort* __restrict__ Cp)
{
  int i = blockIdx.x * 256 + threadIdx.x;
  ushort* buf; int HPx, idx;
  if (i < 16 * 42 * 42) { buf = hidP; HPx = 42; idx = i; }
  else if (i < 16 * 42 * 42 + 16 * 82 * 82) {
    buf = Ap; HPx = 82; idx = i - 16 * 42 * 42;
  } else if (i < 16 * 42 * 42 + 16 * 82 * 82 + 16 * 162 * 162) {
    buf = Cp; HPx = 162; idx = i - 16 * 42 * 42 - 16 * 82 * 82;
  } else return;
  int p = idx % (HPx * HPx);
  int y = p / HPx, x = p - y * HPx;
  if (y == 0 || y == HPx - 1 || x == 0 || x == HPx - 1) {
    uint4 z = {0u, 0u, 0u, 0u};
    uint4* dst = (uint4*)(buf + (size_t)idx * 64);
    #pragma unroll
    for (int k = 0; k < 8; ++k) dst[k] = z;
  }
}

// ---- slot-summed GN stats -> (mean, rstd) ---------------------------------
DEVFN void gn_stats(const float* __restrict__ st, int bg, float N,
                    float& mean, float& rstd) {
  float s = 0.f, q = 0.f;
  #pragma unroll
  for (int sl = 0; sl < 8; ++sl) {
    s += st[sl * 64 + bg * 2 + 0];
    q += st[sl * 64 + bg * 2 + 1];
  }
  float m = s / N;
  mean = m;
  rstd = rsqrtf(q / N - m * m + 1e-5f);
}

// ---- act: NCHW (f32 or bf16) -> padded NHWC bf16 via swizzled LDS ---------
// MODE: 0 copy (pad only); 1 GN+SiLU; 2 GN+SiLU + addsrc(f32)
template<int HW_TOT, int WOUT, int MODE, typename T>
__global__ __launch_bounds__(256)
void act_k(const T* __restrict__ in, const float* __restrict__ st,
           const float* __restrict__ gw, const float* __restrict__ gb,
           const float* __restrict__ addsrc, ushort* __restrict__ outP)
{
  constexpr int HOUT = HW_TOT / WOUT;
  constexpr int WP = WOUT + 2, HP = HOUT + 2;
  __shared__ uint4 sT[256 * 8];            // [pixel][slot], slot = cc ^ (pix&7)
  const int tid = threadIdx.x;
  constexpr int NBLK = (HW_TOT + 255) / 256;
  const int b  = blockIdx.x / NBLK;
  const int p0 = (blockIdx.x - b * NBLK) * 256;
  const int px = p0 + tid;

  float mean[2], rstd[2];
  if (MODE >= 1) {
    const float N = 32.f * HW_TOT;
    #pragma unroll
    for (int g = 0; g < 2; ++g) gn_stats(st, b * 2 + g, N, mean[g], rstd[g]);
  }
  if (px < HW_TOT) {
    const T* ip = in + (size_t)b * 64 * HW_TOT + px;
    #pragma unroll 2
    for (int cc = 0; cc < 8; ++cc) {
      unsigned w[4];
      #pragma unroll
      for (int jp = 0; jp < 4; ++jp) {
        float v0, v1;
        #pragma unroll
        for (int h = 0; h < 2; ++h) {
          int c = cc * 8 + jp * 2 + h;
          float v = ldf(ip[(size_t)c * HW_TOT]);
          if (MODE >= 1) {
            v = silu_f((v - mean[c >> 5]) * rstd[c >> 5] * gw[c] + gb[c]);
            if (MODE == 2) v += addsrc[(size_t)(b * 64 + c) * HW_TOT + px];
          }
          if (h == 0) v0 = v; else v1 = v;
        }
        w[jp] = (unsigned)f2bf(v0) | ((unsigned)f2bf(v1) << 16);
      }
      uint4 pk = {w[0], w[1], w[2], w[3]};
      sT[tid * 8 + (cc ^ (tid & 7))] = pk;
    }
  }
  __syncthreads();
  const int o = tid & 7, pr = tid >> 3;
  #pragma unroll
  for (int i = 0; i < 8; ++i) {
    int p = i * 32 + pr;
    int gpx = p0 + p;
    if (gpx < HW_TOT) {
      int y = gpx / WOUT, x = gpx - y * WOUT;
      uint4 val = sT[p * 8 + (o ^ (p & 7))];
      *(uint4*)(outP + (((size_t)(b * HP) + y + 1) * WP + (x + 1)) * 64 + o * 8) = val;
    }
  }
}

// ---- MFMA implicit-GEMM 3x3 conv, single-staged row strip -----------------
// In: padded NHWC bf16. Out: bf16 NCHW, PRE-NORM (stats fused, f32 accs).

#define FE18(M) M(0) M(1) M(2) M(3) M(4) M(5) M(6) M(7) M(8) M(9) M(10) \
                M(11) M(12) M(13) M(14) M(15) M(16) M(17)

#define WDL(t) \
  v8s Wa##t = ((const v8s*)wrep)[(size_t)((t) * 4 + sub) * OCT + ocbase + lx]; \
  v8s Wb##t = ((const v8s*)wrep)[(size_t)((t) * 4 + sub) * OCT + ocbase + 16 + lx];

// step t: tap = t>>1 (dy=t/6, dx=(t>>1)%3), icc-half = t&1
#define KST(t) { \
    const int col_ = lx + (((t) >> 1) % 3); \
    v8s b_ = __builtin_bit_cast(v8s, sQ[((rbase + wrow + (t) / 6) * LWS + xb + col_) * 8 + \
                                        (((((t) & 1) * 4 + sub)) ^ ((xb + col_) & 7))]); \
    a0 = __builtin_amdgcn_mfma_f32_16x16x32_bf16(Wa##t, b_, a0, 0, 0, 0); \
    a1 = __builtin_amdgcn_mfma_f32_16x16x32_bf16(Wb##t, b_, a1, 0, 0, 0); }

template<int HIN, int WIN, int WT, int NG, int RPB, int OCT, bool PSF,
         int WEU_MIN, int WEU_MAX>
__global__
__attribute__((amdgpu_flat_work_group_size(256, 256),
               amdgpu_waves_per_eu(WEU_MIN, WEU_MAX)))
void convm_k(const uint4* __restrict__ inP, const ushort* __restrict__ wrep,
             const float* __restrict__ bias, ushort* __restrict__ out,
             float* __restrict__ stp)
{
  constexpr int HP = HIN + 2, WP = WIN + 2;
  constexpr int LH = RPB + 2, LW = WT + 2;
  constexpr int NOCB = OCT / 64;
  constexpr int LRD = (NG * 16 + 2 > LW) ? (NG * 16 + 2) : LW;
  constexpr int LWS = (LRD + 7) & ~7;      // multiple of 8: (pix&7)==(col&7)
  constexpr int NCHUNK = LH * LWS * 8;
  static_assert(NCHUNK % 256 == 0, "staging must tile evenly");
  constexpr int STK = NCHUNK / 256;
  __shared__ uint4 sQ[NCHUNK];
  __shared__ float red[4][2];

  const int tid  = threadIdx.x;
  const int lane = tid & 63;
  const int wave = tid >> 6;
  const int sub  = lane >> 4;
  const int lx   = lane & 15;
  const int wrow = wave >> 1;              // row within pair
  const int b    = blockIdx.y / NOCB;
  const int ocb  = blockIdx.y - b * NOCB;
  constexpr int NTX = WIN / WT;
  const int tx    = blockIdx.x % NTX;
  const int ych   = blockIdx.x / NTX;
  const int x0    = tx * WT;
  const int ybase = ych * RPB;
  const int ocbase = ocb * 64 + (wave & 1) * 32;

  // staging FIRST: batched loads -> LDS (staging regs die here)
  const uint4* gbase = inP + ((size_t)(b * HP + ybase) * WP + x0) * 8;
  {
    uint4 stg[STK];
    #pragma unroll
    for (int k = 0; k < STK; ++k) {
      int q = tid + k * 256;
      int p = q >> 3, cc = q & 7;
      int r = p / LWS, cx = p - r * LWS;
      stg[k] = gbase[((size_t)r * WP + cx) * 8 + cc];
    }
    #pragma unroll
    for (int k = 0; k < STK; ++k) {
      int q = tid + k * 256;
      int p = q >> 3, cc = q & 7;
      int cx = p - (p / LWS) * LWS;
      sQ[p * 8 + (cc ^ (cx & 7))] = stg[k];
    }
  }

  // weights AFTER staging (overlap LDS-write drain, pre-barrier)
  FE18(WDL)

  const v4f bi0 = *(const v4f*)&bias[ocbase + sub * 4];
  const v4f bi1 = *(const v4f*)&bias[ocbase + 16 + sub * 4];

  __syncthreads();

  float sA = 0.f, qA = 0.f;

  for (int it = 0; it < RPB / 2; ++it) {
    const int rbase = it * 2;
    const int y = ybase + rbase + wrow;
    for (int xg = 0; xg < NG; ++xg) {
      const int xb = xg * 16;
      v4f a0 = bi0, a1 = bi1;
      FE18(KST)
      const int x = x0 + xb + lx;
      if ((NG * 16 == WT) || (x < WIN)) {
        #pragma unroll
        for (int s = 0; s < 2; ++s) {
          const v4f a = s ? a1 : a0;
          if (!PSF) {
            #pragma unroll
            for (int j = 0; j < 4; ++j) {
              int oc = ocbase + s * 16 + sub * 4 + j;
              out[((size_t)(b * OCT + oc) * HIN + y) * WIN + x] = f2bf(a[j]);
            }
          } else {
            // lane owns the full 2x2 quad of plane c
            const int c = (ocbase + s * 16 + sub * 4) >> 2;
            unsigned top = (unsigned)f2bf(a[0]) | ((unsigned)f2bf(a[1]) << 16);
            unsigned bot = (unsigned)f2bf(a[2]) | ((unsigned)f2bf(a[3]) << 16);
            const size_t qb =
              ((size_t)(b * 64 + c) * (2 * HIN) + 2 * y) * (2 * WIN) + 2 * x;
            *(unsigned*)(out + qb) = top;
            *(unsigned*)(out + qb + 2 * WIN) = bot;
          }
          #pragma unroll
          for (int j = 0; j < 4; ++j) { sA += a[j]; qA += a[j] * a[j]; }
        }
      }
    }
  }

  // GroupNorm stats (f32 accumulators, exact)
  #pragma unroll
  for (int o = 32; o >= 1; o >>= 1) {
    sA += __shfl_down(sA, o);
    qA += __shfl_down(qA, o);
  }
  if (lane == 0) { red[wave][0] = sA; red[wave][1] = qA; }
  __syncthreads();
  if (tid == 0) {
    float* basep = stp + ((blockIdx.x ^ blockIdx.y) & 7) * 64;
    if (PSF) {
      int g = ocb >> 1;
      atomicAdd(&basep[(b * 2 + g) * 2 + 0],
                red[0][0] + red[1][0] + red[2][0] + red[3][0]);
      atomicAdd(&basep[(b * 2 + g) * 2 + 1],
                red[0][1] + red[1][1] + red[2][1] + red[3][1]);
    } else {
      atomicAdd(&basep[(b * 2 + 0) * 2 + 0], red[0][0] + red[2][0]);
      atomicAdd(&basep[(b * 2 + 0) * 2 + 1], red[0][1] + red[2][1]);
      atomicAdd(&basep[(b * 2 + 1) * 2 + 0], red[1][0] + red[3][0]);
      atomicAdd(&basep[(b * 2 + 1) * 2 + 1], red[1][1] + red[3][1]);
    }
  }
}

// ---- readout, 2 pixels/thread (u32 bf16x2 plane loads) --------------------
__global__ __launch_bounds__(256)
void readout_k(const ushort* __restrict__ D, const float* __restrict__ st,
               const float* __restrict__ gw, const float* __restrict__ gb,
               const float* __restrict__ rw, const float* __restrict__ rb,
               float* __restrict__ Y)
{
  int idx = blockIdx.x * 256 + threadIdx.x;
  if (idx >= 16 * 12800) return;
  int b = idx / 12800, pp = (idx - b * 12800) * 2;
  const float N = 32.f * 25600.f;
  float mean[2], rstd[2];
  #pragma unroll
  for (int g = 0; g < 2; ++g) gn_stats(st, b * 2 + g, N, mean[g], rstd[g]);
  float a0 = rb[0], a1 = rb[1], a2 = rb[2];
  float c0a = rb[0], c1a = rb[1], c2a = rb[2];
  const ushort* dp = D + (size_t)(b * 64) * 25600 + pp;
  #pragma unroll 4
  for (int c = 0; c < 64; ++c) {
    unsigned w = *(const unsigned*)(dp + (size_t)c * 25600);
    float m = mean[c >> 5], rs = rstd[c >> 5];
    float v0 = silu_f((bf2f(w & 0xffffu) - m) * rs * gw[c] + gb[c]);
    float v1 = silu_f((bf2f(w >> 16) - m) * rs * gw[c] + gb[c]);
    a0  = fmaf(v0, rw[c], a0);        c0a = fmaf(v1, rw[c], c0a);
    a1  = fmaf(v0, rw[64 + c], a1);   c1a = fmaf(v1, rw[64 + c], c1a);
    a2  = fmaf(v0, rw[128 + c], a2);  c2a = fmaf(v1, rw[128 + c], c2a);
  }
  float2* y0 = (float2*)&Y[(size_t)(b * 3 + 0) * 25600 + pp];
  float2* y1 = (float2*)&Y[(size_t)(b * 3 + 1) * 25600 + pp];
  float2* y2 = (float2*)&Y[(size_t)(b * 3 + 2) * 25600 + pp];
  *y0 = make_float2(a0, c0a);
  *y1 = make_float2(a1, c1a);
  *y2 = make_float2(a2, c2a);
}

// ---- feamap: argx = conv(Y, fw, stride 4)/16, first 3 channels ------------
__global__ void feamap_k(const float* __restrict__ Y, const float* __restrict__ fw,
                         float* __restrict__ argx)
{
  int idx = blockIdx.x * 256 + threadIdx.x;
  if (idx >= 16 * 3 * 1600) return;
  int b  = idx / (3 * 1600);
  int o  = (idx / 1600) % 3;
  int ij = idx % 1600;
  int i = ij / 40, j = ij - i * 40;
  float s = 0.f;
  #pragma unroll
  for (int c = 0; c < 3; ++c)
    #pragma unroll
    for (int u = 0; u < 4; ++u)
      #pragma unroll
      for (int v = 0; v < 4; ++v)
        s += Y[((size_t)(b * 3 + c) * 160 + (4 * i + u)) * 160 + (4 * j + v)]
             * fw[((o * 3 + c) * 4 + u) * 4 + v];
  argx[idx] = s * (1.f / 16.f);
}

// ---- final: nz folded in (count nonzeros of the attn row we already read) -
__global__ void final_k(const float* __restrict__ Y, const float* __restrict__ attn,
                        const float* __restrict__ argx, float* __restrict__ out)
{
  int idx = blockIdx.x * 256 + threadIdx.x;
  if (idx >= 16 * 3 * 25600) return;
  int bc  = idx / 25600;
  int pix = idx - bc * 25600;
  int y = pix / 160, x = pix - y * 160;
  int l  = (y / 10) * 16 + (x / 10);
  int pi = y % 10,  pj = x % 10;
  const float* ar = attn + ((size_t)bc * 256 + l) * 16;
  const float* ax = argx + (size_t)bc * 1600;
  float corr = 0.f;
  int cnt = 0;
  #pragma unroll
  for (int k = 0; k < 16; ++k) {
    float av = ar[k];
    cnt += (av != 0.f);
    corr += av * ax[((k >> 2) * 10 + pi) * 40 + ((k & 3) * 10 + pj)];
  }
  float inv = 1.f / ((float)cnt + 1e-5f);
  float yv = Y[idx];
  out[idx] = yv * (1.f + corr * inv);
}

// ---------------------------------------------------------------------------
extern "C" void kernel_launch(void* const* d_in, const int* in_sizes, int n_in,
                              void* d_out, int out_size, void* d_ws, size_t ws_size,
                              hipStream_t stream)
{
  const float* attn = (const float*)d_in[0];
  const float* hid  = (const float*)d_in[1];
  const float* enc1 = (const float*)d_in[2];
  const float* d0w  = (const float*)d_in[3];
  const float* d0b  = (const float*)d_in[4];
  const float* d0gw = (const float*)d_in[5];
  const float* d0gb = (const float*)d_in[6];
  const float* d1w  = (const float*)d_in[7];
  const float* d1b  = (const float*)d_in[8];
  const float* d1gw = (const float*)d_in[9];
  const float* d1gb = (const float*)d_in[10];
  const float* d2w  = (const float*)d_in[11];
  const float* d2b  = (const float*)d_in[12];
  const float* d2gw = (const float*)d_in[13];
  const float* d2gb = (const float*)d_in[14];
  const float* d3w  = (const float*)d_in[15];
  const float* d3b  = (const float*)d_in[16];
  const float* d3gw = (const float*)d_in[17];
  const float* d3gb = (const float*)d_in[18];
  const float* rw   = (const float*)d_in[19];
  const float* rb   = (const float*)d_in[20];
  const float* fw   = (const float*)d_in[21];

  float* ws = (float*)d_ws;
  size_t o = 0;
  float* bufA  = ws + o; o += (size_t)16 * 64 * 80 * 80;       // A/Bb (bf16) + Y/argx (f32)
  float* bufAp = ws + o; o += (size_t)16 * 82 * 82 * 64 / 2;   // Ap / Bp  (NHWC bf16)
  float* bufC  = ws + o; o += (size_t)16 * 64 * 160 * 160 / 2; // Cb / Db (NCHW bf16)
  float* bufCp = ws + o; o += (size_t)16 * 162 * 162 * 64 / 2; // Cp (NHWC bf16)
  float* hidPf = ws + o; o += (size_t)16 * 42 * 42 * 64 / 2;   // hidP
  float* st    = ws + o; o += 4 * 512;                         // slotted stats
  float* w0f   = ws + o; o += (size_t)72 * 256 * 8 / 2;
  float* w1f   = ws + o; o += (size_t)72 * 64 * 8 / 2;
  float* w2f   = ws + o; o += (size_t)72 * 256 * 8 / 2;
  float* w3f   = ws + o; o += (size_t)72 * 64 * 8 / 2;

  ushort* A    = (ushort*)bufA;            // bf16 NCHW [16,64,80,80]
  ushort* Bb   = (ushort*)bufA;            // aliases A (A dead after act1)
  ushort* Ap   = (ushort*)bufAp;
  ushort* Bp   = (ushort*)bufAp;
  ushort* Cb   = (ushort*)bufC;
  ushort* Db   = (ushort*)bufC;
  ushort* Cp   = (ushort*)bufCp;
  ushort* hidP = (ushort*)hidPf;
  float*  Y    = bufA;                     // Bb dead after act2
  float*  argx = bufA + (size_t)16 * 3 * 25600;
  ushort* wr0  = (ushort*)w0f;
  ushort* wr1  = (ushort*)w1f;
  ushort* wr2  = (ushort*)w2f;
  ushort* wr3  = (ushort*)w3f;

  // fused prep: zero stats + repack 4 weight tensors (368640 elems)
  prep_k<<<(368640 + 255) / 256, 256, 0, stream>>>(d0w, d1w, d2w, d3w,
                                                   wr0, wr1, wr2, wr3, st);

  // fused borders for hidP / Ap(+Bp) / Cp
  border3_k<<<(16 * (42 * 42 + 82 * 82 + 162 * 162) + 255) / 256, 256, 0,
              stream>>>(hidP, Ap, Cp);

  // pad hid -> hidP (NHWC bf16)
  act_k<1600, 40, 0, float><<<16 * 7, 256, 0, stream>>>(
      hid, nullptr, nullptr, nullptr, nullptr, hidP);

  // stage 0: conv(hidP)+PS -> A (bf16 NCHW, pre-norm), stats st0
  convm_k<40, 40, 40, 3, 10, 256, true, 1, 1>
    <<<dim3(4, 16 * 4), 256, 0, stream>>>((const uint4*)hidP, wr0, d0b, A,
                                          st + 0 * 512);

  // act1: GN+SiLU(A) -> Ap (NHWC)
  act_k<6400, 80, 1, ushort><<<16 * 25, 256, 0, stream>>>(
      A, st + 0 * 512, d0gw, d0gb, nullptr, Ap);

  // stage 1: conv(Ap) -> Bb, stats st1
  convm_k<80, 80, 16, 1, 10, 64, false, 2, 8>
    <<<dim3(40, 16), 256, 0, stream>>>((const uint4*)Ap, wr1, d1b, Bb,
                                       st + 1 * 512);

  // act2: GN+SiLU(Bb) -> Bp
  act_k<6400, 80, 1, ushort><<<16 * 25, 256, 0, stream>>>(
      Bb, st + 1 * 512, d1gw, d1gb, nullptr, Bp);

  // stage 2: conv(Bp)+PS -> Cb, stats st2
  convm_k<80, 80, 16, 1, 10, 256, true, 2, 8>
    <<<dim3(40, 16 * 4), 256, 0, stream>>>((const uint4*)Bp, wr2, d2b, Cb,
                                           st + 2 * 512);

  // act3: GN+SiLU(Cb) + enc1 -> Cp
  act_k<25600, 160, 2, ushort><<<16 * 100, 256, 0, stream>>>(
      Cb, st + 2 * 512, d2gw, d2gb, enc1, Cp);

  // stage 3: conv(Cp) -> Db, stats st3
  convm_k<160, 160, 16, 1, 10, 64, false, 2, 8>
    <<<dim3(160, 16), 256, 0, stream>>>((const uint4*)Cp, wr3, d3b, Db,
                                        st + 3 * 512);

  // readout: Y = 1x1conv(GN_SiLU(Db)), 2 px/thread
  readout_k<<<(16 * 12800 + 255) / 256, 256, 0, stream>>>(Db, st + 3 * 512,
      d3gw, d3gb, rw, rb, Y);

  feamap_k<<<(16 * 3 * 1600 + 255) / 256, 256, 0, stream>>>(Y, fw, argx);
  final_k<<<(16 * 3 * 25600 + 255) / 256, 256, 0, stream>>>(Y, attn, argx,
      (float*)d_out);
}

// Round 21
// 235.538 us; speedup vs baseline: 1.0858x; 1.0384x over previous
//
#include <hip/hip_runtime.h>

// ---------------------------------------------------------------------------
// SimVP Decoder, round 21: R20 (244us, best) + stage-3 conv WT=32 (NG=2).
// Stage 3 was 2560 blocks of 16-px tiles: prologue (stage + 36 weight loads
// + barrier) amortized over 160 px/wave. WT=32 halves block count, halves
// per-pixel prologue cost, improves halo ratio 1.8->1.5 staged-px/output-px.
// Uses the existing NG>1 path (proven by stage 0 since R11); LDS 61.4KB
// (still 2 blocks/CU), VGPR unchanged. 80-wide stages keep WT=16.
// Everything else byte-identical to R20 (passed, absmax 0.0078).
// ---------------------------------------------------------------------------

#define DEVFN static __device__ __forceinline__

typedef short v8s __attribute__((ext_vector_type(8)));
typedef float v4f __attribute__((ext_vector_type(4)));

DEVFN float silu_f(float t) { return t / (1.f + __expf(-t)); }

DEVFN ushort f2bf(float x) {
  union { float f; unsigned u; } t; t.f = x;
  unsigned r = t.u + 0x7FFFu + ((t.u >> 16) & 1u);
  return (ushort)(r >> 16);
}

DEVFN float bf2f(unsigned u) {
  union { unsigned i; float f; } t; t.i = u << 16; return t.f;
}

DEVFN float ldf(float x) { return x; }
DEVFN float ldf(ushort u) { return bf2f(u); }

// ---- fused prep: zero stats + repack all 4 weight tensors -----------------
DEVFN void repack1(const float* __restrict__ src, ushort* __restrict__ dst,
                   int i, int OC) {
  int oc = i / 576, r = i - oc * 576;      // r = ic*9 + tap
  int ic = r / 9, tap = r - ic * 9;
  int kc = tap * 8 + (ic >> 3), j = ic & 7;
  dst[((size_t)kc * OC + oc) * 8 + j] = f2bf(src[i]);
}

__global__ __launch_bounds__(256)
void prep_k(const float* __restrict__ s0, const float* __restrict__ s1,
            const float* __restrict__ s2, const float* __restrict__ s3,
            ushort* __restrict__ d0, ushort* __restrict__ d1,
            ushort* __restrict__ d2, ushort* __restrict__ d3,
            float* __restrict__ st)
{
  int i = blockIdx.x * 256 + threadIdx.x;
  if (i < 2048) st[i] = 0.f;
  int j = i;
  if (j < 147456) { repack1(s0, d0, j, 256); return; }
  j -= 147456;
  if (j < 36864)  { repack1(s1, d1, j, 64);  return; }
  j -= 36864;
  if (j < 147456) { repack1(s2, d2, j, 256); return; }
  j -= 147456;
  if (j < 36864)  { repack1(s3, d3, j, 64);  return; }
}

// ---- fused border zeroing for the 3 padded NHWC buffers -------------------
__global__ __launch_bounds__(256)
void border3_k(ushort* __restrict__ hidP, ushort* __restrict__ Ap,
               ushort* __restrict__ Cp)
{
  int i = blockIdx.x * 256 + threadIdx.x;
  ushort* buf; int HPx, idx;
  if (i < 16 * 42 * 42) { buf = hidP; HPx = 42; idx = i; }
  else if (i < 16 * 42 * 42 + 16 * 82 * 82) {
    buf = Ap; HPx = 82; idx = i - 16 * 42 * 42;
  } else if (i < 16 * 42 * 42 + 16 * 82 * 82 + 16 * 162 * 162) {
    buf = Cp; HPx = 162; idx = i - 16 * 42 * 42 - 16 * 82 * 82;
  } else return;
  int p = idx % (HPx * HPx);
  int y = p / HPx, x = p - y * HPx;
  if (y == 0 || y == HPx - 1 || x == 0 || x == HPx - 1) {
    uint4 z = {0u, 0u, 0u, 0u};
    uint4* dst = (uint4*)(buf + (size_t)idx * 64);
    #pragma unroll
    for (int k = 0; k < 8; ++k) dst[k] = z;
  }
}

// ---- slot-summed GN stats -> (mean, rstd) ---------------------------------
DEVFN void gn_stats(const float* __restrict__ st, int bg, float N,
                    float& mean, float& rstd) {
  float s = 0.f, q = 0.f;
  #pragma unroll
  for (int sl = 0; sl < 8; ++sl) {
    s += st[sl * 64 + bg * 2 + 0];
    q += st[sl * 64 + bg * 2 + 1];
  }
  float m = s / N;
  mean = m;
  rstd = rsqrtf(q / N - m * m + 1e-5f);
}

// ---- act: NCHW (f32 or bf16) -> padded NHWC bf16 via swizzled LDS ---------
// MODE: 0 copy (pad only); 1 GN+SiLU; 2 GN+SiLU + addsrc(f32)
template<int HW_TOT, int WOUT, int MODE, typename T>
__global__ __launch_bounds__(256)
void act_k(const T* __restrict__ in, const float* __restrict__ st,
           const float* __restrict__ gw, const float* __restrict__ gb,
           const float* __restrict__ addsrc, ushort* __restrict__ outP)
{
  constexpr int HOUT = HW_TOT / WOUT;
  constexpr int WP = WOUT + 2, HP = HOUT + 2;
  __shared__ uint4 sT[256 * 8];            // [pixel][slot], slot = cc ^ (pix&7)
  const int tid = threadIdx.x;
  constexpr int NBLK = (HW_TOT + 255) / 256;
  const int b  = blockIdx.x / NBLK;
  const int p0 = (blockIdx.x - b * NBLK) * 256;
  const int px = p0 + tid;

  float mean[2], rstd[2];
  if (MODE >= 1) {
    const float N = 32.f * HW_TOT;
    #pragma unroll
    for (int g = 0; g < 2; ++g) gn_stats(st, b * 2 + g, N, mean[g], rstd[g]);
  }
  if (px < HW_TOT) {
    const T* ip = in + (size_t)b * 64 * HW_TOT + px;
    #pragma unroll 2
    for (int cc = 0; cc < 8; ++cc) {
      unsigned w[4];
      #pragma unroll
      for (int jp = 0; jp < 4; ++jp) {
        float v0, v1;
        #pragma unroll
        for (int h = 0; h < 2; ++h) {
          int c = cc * 8 + jp * 2 + h;
          float v = ldf(ip[(size_t)c * HW_TOT]);
          if (MODE >= 1) {
            v = silu_f((v - mean[c >> 5]) * rstd[c >> 5] * gw[c] + gb[c]);
            if (MODE == 2) v += addsrc[(size_t)(b * 64 + c) * HW_TOT + px];
          }
          if (h == 0) v0 = v; else v1 = v;
        }
        w[jp] = (unsigned)f2bf(v0) | ((unsigned)f2bf(v1) << 16);
      }
      uint4 pk = {w[0], w[1], w[2], w[3]};
      sT[tid * 8 + (cc ^ (tid & 7))] = pk;
    }
  }
  __syncthreads();
  const int o = tid & 7, pr = tid >> 3;
  #pragma unroll
  for (int i = 0; i < 8; ++i) {
    int p = i * 32 + pr;
    int gpx = p0 + p;
    if (gpx < HW_TOT) {
      int y = gpx / WOUT, x = gpx - y * WOUT;
      uint4 val = sT[p * 8 + (o ^ (p & 7))];
      *(uint4*)(outP + (((size_t)(b * HP) + y + 1) * WP + (x + 1)) * 64 + o * 8) = val;
    }
  }
}

// ---- MFMA implicit-GEMM 3x3 conv, single-staged row strip -----------------
// In: padded NHWC bf16. Out: bf16 NCHW, PRE-NORM (stats fused, f32 accs).

#define FE18(M) M(0) M(1) M(2) M(3) M(4) M(5) M(6) M(7) M(8) M(9) M(10) \
                M(11) M(12) M(13) M(14) M(15) M(16) M(17)

#define WDL(t) \
  v8s Wa##t = ((const v8s*)wrep)[(size_t)((t) * 4 + sub) * OCT + ocbase + lx]; \
  v8s Wb##t = ((const v8s*)wrep)[(size_t)((t) * 4 + sub) * OCT + ocbase + 16 + lx];

// step t: tap = t>>1 (dy=t/6, dx=(t>>1)%3), icc-half = t&1
#define KST(t) { \
    const int col_ = lx + (((t) >> 1) % 3); \
    v8s b_ = __builtin_bit_cast(v8s, sQ[((rbase + wrow + (t) / 6) * LWS + xb + col_) * 8 + \
                                        (((((t) & 1) * 4 + sub)) ^ ((xb + col_) & 7))]); \
    a0 = __builtin_amdgcn_mfma_f32_16x16x32_bf16(Wa##t, b_, a0, 0, 0, 0); \
    a1 = __builtin_amdgcn_mfma_f32_16x16x32_bf16(Wb##t, b_, a1, 0, 0, 0); }

template<int HIN, int WIN, int WT, int NG, int RPB, int OCT, bool PSF,
         int WEU_MIN, int WEU_MAX>
__global__
__attribute__((amdgpu_flat_work_group_size(256, 256),
               amdgpu_waves_per_eu(WEU_MIN, WEU_MAX)))
void convm_k(const uint4* __restrict__ inP, const ushort* __restrict__ wrep,
             const float* __restrict__ bias, ushort* __restrict__ out,
             float* __restrict__ stp)
{
  constexpr int HP = HIN + 2, WP = WIN + 2;
  constexpr int LH = RPB + 2, LW = WT + 2;
  constexpr int NOCB = OCT / 64;
  constexpr int LRD = (NG * 16 + 2 > LW) ? (NG * 16 + 2) : LW;
  constexpr int LWS = (LRD + 7) & ~7;      // multiple of 8: (pix&7)==(col&7)
  constexpr int NCHUNK = LH * LWS * 8;
  static_assert(NCHUNK % 256 == 0, "staging must tile evenly");
  constexpr int STK = NCHUNK / 256;
  __shared__ uint4 sQ[NCHUNK];
  __shared__ float red[4][2];

  const int tid  = threadIdx.x;
  const int lane = tid & 63;
  const int wave = tid >> 6;
  const int sub  = lane >> 4;
  const int lx   = lane & 15;
  const int wrow = wave >> 1;              // row within pair
  const int b    = blockIdx.y / NOCB;
  const int ocb  = blockIdx.y - b * NOCB;
  constexpr int NTX = WIN / WT;
  const int tx    = blockIdx.x % NTX;
  const int ych   = blockIdx.x / NTX;
  const int x0    = tx * WT;
  const int ybase = ych * RPB;
  const int ocbase = ocb * 64 + (wave & 1) * 32;

  // staging FIRST: batched loads -> LDS (staging regs die here)
  const uint4* gbase = inP + ((size_t)(b * HP + ybase) * WP + x0) * 8;
  {
    uint4 stg[STK];
    #pragma unroll
    for (int k = 0; k < STK; ++k) {
      int q = tid + k * 256;
      int p = q >> 3, cc = q & 7;
      int r = p / LWS, cx = p - r * LWS;
      stg[k] = gbase[((size_t)r * WP + cx) * 8 + cc];
    }
    #pragma unroll
    for (int k = 0; k < STK; ++k) {
      int q = tid + k * 256;
      int p = q >> 3, cc = q & 7;
      int cx = p - (p / LWS) * LWS;
      sQ[p * 8 + (cc ^ (cx & 7))] = stg[k];
    }
  }

  // weights AFTER staging (overlap LDS-write drain, pre-barrier)
  FE18(WDL)

  const v4f bi0 = *(const v4f*)&bias[ocbase + sub * 4];
  const v4f bi1 = *(const v4f*)&bias[ocbase + 16 + sub * 4];

  __syncthreads();

  float sA = 0.f, qA = 0.f;

  for (int it = 0; it < RPB / 2; ++it) {
    const int rbase = it * 2;
    const int y = ybase + rbase + wrow;
    for (int xg = 0; xg < NG; ++xg) {
      const int xb = xg * 16;
      v4f a0 = bi0, a1 = bi1;
      FE18(KST)
      const int x = x0 + xb + lx;
      if ((NG * 16 == WT) || (x < WIN)) {
        #pragma unroll
        for (int s = 0; s < 2; ++s) {
          const v4f a = s ? a1 : a0;
          if (!PSF) {
            #pragma unroll
            for (int j = 0; j < 4; ++j) {
              int oc = ocbase + s * 16 + sub * 4 + j;
              out[((size_t)(b * OCT + oc) * HIN + y) * WIN + x] = f2bf(a[j]);
            }
          } else {
            // lane owns the full 2x2 quad of plane c
            const int c = (ocbase + s * 16 + sub * 4) >> 2;
            unsigned top = (unsigned)f2bf(a[0]) | ((unsigned)f2bf(a[1]) << 16);
            unsigned bot = (unsigned)f2bf(a[2]) | ((unsigned)f2bf(a[3]) << 16);
            const size_t qb =
              ((size_t)(b * 64 + c) * (2 * HIN) + 2 * y) * (2 * WIN) + 2 * x;
            *(unsigned*)(out + qb) = top;
            *(unsigned*)(out + qb + 2 * WIN) = bot;
          }
          #pragma unroll
          for (int j = 0; j < 4; ++j) { sA += a[j]; qA += a[j] * a[j]; }
        }
      }
    }
  }

  // GroupNorm stats (f32 accumulators, exact)
  #pragma unroll
  for (int o = 32; o >= 1; o >>= 1) {
    sA += __shfl_down(sA, o);
    qA += __shfl_down(qA, o);
  }
  if (lane == 0) { red[wave][0] = sA; red[wave][1] = qA; }
  __syncthreads();
  if (tid == 0) {
    float* basep = stp + ((blockIdx.x ^ blockIdx.y) & 7) * 64;
    if (PSF) {
      int g = ocb >> 1;
      atomicAdd(&basep[(b * 2 + g) * 2 + 0],
                red[0][0] + red[1][0] + red[2][0] + red[3][0]);
      atomicAdd(&basep[(b * 2 + g) * 2 + 1],
                red[0][1] + red[1][1] + red[2][1] + red[3][1]);
    } else {
      atomicAdd(&basep[(b * 2 + 0) * 2 + 0], red[0][0] + red[2][0]);
      atomicAdd(&basep[(b * 2 + 0) * 2 + 1], red[0][1] + red[2][1]);
      atomicAdd(&basep[(b * 2 + 1) * 2 + 0], red[1][0] + red[3][0]);
      atomicAdd(&basep[(b * 2 + 1) * 2 + 1], red[1][1] + red[3][1]);
    }
  }
}

// ---- readout, 2 pixels/thread (u32 bf16x2 plane loads) --------------------
__global__ __launch_bounds__(256)
void readout_k(const ushort* __restrict__ D, const float* __restrict__ st,
               const float* __restrict__ gw, const float* __restrict__ gb,
               const float* __restrict__ rw, const float* __restrict__ rb,
               float* __restrict__ Y)
{
  int idx = blockIdx.x * 256 + threadIdx.x;
  if (idx >= 16 * 12800) return;
  int b = idx / 12800, pp = (idx - b * 12800) * 2;
  const float N = 32.f * 25600.f;
  float mean[2], rstd[2];
  #pragma unroll
  for (int g = 0; g < 2; ++g) gn_stats(st, b * 2 + g, N, mean[g], rstd[g]);
  float a0 = rb[0], a1 = rb[1], a2 = rb[2];
  float c0a = rb[0], c1a = rb[1], c2a = rb[2];
  const ushort* dp = D + (size_t)(b * 64) * 25600 + pp;
  #pragma unroll 4
  for (int c = 0; c < 64; ++c) {
    unsigned w = *(const unsigned*)(dp + (size_t)c * 25600);
    float m = mean[c >> 5], rs = rstd[c >> 5];
    float v0 = silu_f((bf2f(w & 0xffffu) - m) * rs * gw[c] + gb[c]);
    float v1 = silu_f((bf2f(w >> 16) - m) * rs * gw[c] + gb[c]);
    a0  = fmaf(v0, rw[c], a0);        c0a = fmaf(v1, rw[c], c0a);
    a1  = fmaf(v0, rw[64 + c], a1);   c1a = fmaf(v1, rw[64 + c], c1a);
    a2  = fmaf(v0, rw[128 + c], a2);  c2a = fmaf(v1, rw[128 + c], c2a);
  }
  float2* y0 = (float2*)&Y[(size_t)(b * 3 + 0) * 25600 + pp];
  float2* y1 = (float2*)&Y[(size_t)(b * 3 + 1) * 25600 + pp];
  float2* y2 = (float2*)&Y[(size_t)(b * 3 + 2) * 25600 + pp];
  *y0 = make_float2(a0, c0a);
  *y1 = make_float2(a1, c1a);
  *y2 = make_float2(a2, c2a);
}

// ---- feamap: argx = conv(Y, fw, stride 4)/16, first 3 channels ------------
__global__ void feamap_k(const float* __restrict__ Y, const float* __restrict__ fw,
                         float* __restrict__ argx)
{
  int idx = blockIdx.x * 256 + threadIdx.x;
  if (idx >= 16 * 3 * 1600) return;
  int b  = idx / (3 * 1600);
  int o  = (idx / 1600) % 3;
  int ij = idx % 1600;
  int i = ij / 40, j = ij - i * 40;
  float s = 0.f;
  #pragma unroll
  for (int c = 0; c < 3; ++c)
    #pragma unroll
    for (int u = 0; u < 4; ++u)
      #pragma unroll
      for (int v = 0; v < 4; ++v)
        s += Y[((size_t)(b * 3 + c) * 160 + (4 * i + u)) * 160 + (4 * j + v)]
             * fw[((o * 3 + c) * 4 + u) * 4 + v];
  argx[idx] = s * (1.f / 16.f);
}

// ---- final: nz folded in (count nonzeros of the attn row we already read) -
__global__ void final_k(const float* __restrict__ Y, const float* __restrict__ attn,
                        const float* __restrict__ argx, float* __restrict__ out)
{
  int idx = blockIdx.x * 256 + threadIdx.x;
  if (idx >= 16 * 3 * 25600) return;
  int bc  = idx / 25600;
  int pix = idx - bc * 25600;
  int y = pix / 160, x = pix - y * 160;
  int l  = (y / 10) * 16 + (x / 10);
  int pi = y % 10,  pj = x % 10;
  const float* ar = attn + ((size_t)bc * 256 + l) * 16;
  const float* ax = argx + (size_t)bc * 1600;
  float corr = 0.f;
  int cnt = 0;
  #pragma unroll
  for (int k = 0; k < 16; ++k) {
    float av = ar[k];
    cnt += (av != 0.f);
    corr += av * ax[((k >> 2) * 10 + pi) * 40 + ((k & 3) * 10 + pj)];
  }
  float inv = 1.f / ((float)cnt + 1e-5f);
  float yv = Y[idx];
  out[idx] = yv * (1.f + corr * inv);
}

// ---------------------------------------------------------------------------
extern "C" void kernel_launch(void* const* d_in, const int* in_sizes, int n_in,
                              void* d_out, int out_size, void* d_ws, size_t ws_size,
                              hipStream_t stream)
{
  const float* attn = (const float*)d_in[0];
  const float* hid  = (const float*)d_in[1];
  const float* enc1 = (const float*)d_in[2];
  const float* d0w  = (const float*)d_in[3];
  const float* d0b  = (const float*)d_in[4];
  const float* d0gw = (const float*)d_in[5];
  const float* d0gb = (const float*)d_in[6];
  const float* d1w  = (const float*)d_in[7];
  const float* d1b  = (const float*)d_in[8];
  const float* d1gw = (const float*)d_in[9];
  const float* d1gb = (const float*)d_in[10];
  const float* d2w  = (const float*)d_in[11];
  const float* d2b  = (const float*)d_in[12];
  const float* d2gw = (const float*)d_in[13];
  const float* d2gb = (const float*)d_in[14];
  const float* d3w  = (const float*)d_in[15];
  const float* d3b  = (const float*)d_in[16];
  const float* d3gw = (const float*)d_in[17];
  const float* d3gb = (const float*)d_in[18];
  const float* rw   = (const float*)d_in[19];
  const float* rb   = (const float*)d_in[20];
  const float* fw   = (const float*)d_in[21];

  float* ws = (float*)d_ws;
  size_t o = 0;
  float* bufA  = ws + o; o += (size_t)16 * 64 * 80 * 80;       // A/Bb (bf16) + Y/argx (f32)
  float* bufAp = ws + o; o += (size_t)16 * 82 * 82 * 64 / 2;   // Ap / Bp  (NHWC bf16)
  float* bufC  = ws + o; o += (size_t)16 * 64 * 160 * 160 / 2; // Cb / Db (NCHW bf16)
  float* bufCp = ws + o; o += (size_t)16 * 162 * 162 * 64 / 2; // Cp (NHWC bf16)
  float* hidPf = ws + o; o += (size_t)16 * 42 * 42 * 64 / 2;   // hidP
  float* st    = ws + o; o += 4 * 512;                         // slotted stats
  float* w0f   = ws + o; o += (size_t)72 * 256 * 8 / 2;
  float* w1f   = ws + o; o += (size_t)72 * 64 * 8 / 2;
  float* w2f   = ws + o; o += (size_t)72 * 256 * 8 / 2;
  float* w3f   = ws + o; o += (size_t)72 * 64 * 8 / 2;

  ushort* A    = (ushort*)bufA;            // bf16 NCHW [16,64,80,80]
  ushort* Bb   = (ushort*)bufA;            // aliases A (A dead after act1)
  ushort* Ap   = (ushort*)bufAp;
  ushort* Bp   = (ushort*)bufAp;
  ushort* Cb   = (ushort*)bufC;
  ushort* Db   = (ushort*)bufC;
  ushort* Cp   = (ushort*)bufCp;
  ushort* hidP = (ushort*)hidPf;
  float*  Y    = bufA;                     // Bb dead after act2
  float*  argx = bufA + (size_t)16 * 3 * 25600;
  ushort* wr0  = (ushort*)w0f;
  ushort* wr1  = (ushort*)w1f;
  ushort* wr2  = (ushort*)w2f;
  ushort* wr3  = (ushort*)w3f;

  // fused prep: zero stats + repack 4 weight tensors (368640 elems)
  prep_k<<<(368640 + 255) / 256, 256, 0, stream>>>(d0w, d1w, d2w, d3w,
                                                   wr0, wr1, wr2, wr3, st);

  // fused borders for hidP / Ap(+Bp) / Cp
  border3_k<<<(16 * (42 * 42 + 82 * 82 + 162 * 162) + 255) / 256, 256, 0,
              stream>>>(hidP, Ap, Cp);

  // pad hid -> hidP (NHWC bf16)
  act_k<1600, 40, 0, float><<<16 * 7, 256, 0, stream>>>(
      hid, nullptr, nullptr, nullptr, nullptr, hidP);

  // stage 0: conv(hidP)+PS -> A (bf16 NCHW, pre-norm), stats st0
  convm_k<40, 40, 40, 3, 10, 256, true, 1, 1>
    <<<dim3(4, 16 * 4), 256, 0, stream>>>((const uint4*)hidP, wr0, d0b, A,
                                          st + 0 * 512);

  // act1: GN+SiLU(A) -> Ap (NHWC)
  act_k<6400, 80, 1, ushort><<<16 * 25, 256, 0, stream>>>(
      A, st + 0 * 512, d0gw, d0gb, nullptr, Ap);

  // stage 1: conv(Ap) -> Bb, stats st1
  convm_k<80, 80, 16, 1, 10, 64, false, 2, 8>
    <<<dim3(40, 16), 256, 0, stream>>>((const uint4*)Ap, wr1, d1b, Bb,
                                       st + 1 * 512);

  // act2: GN+SiLU(Bb) -> Bp
  act_k<6400, 80, 1, ushort><<<16 * 25, 256, 0, stream>>>(
      Bb, st + 1 * 512, d1gw, d1gb, nullptr, Bp);

  // stage 2: conv(Bp)+PS -> Cb, stats st2
  convm_k<80, 80, 16, 1, 10, 256, true, 2, 8>
    <<<dim3(40, 16 * 4), 256, 0, stream>>>((const uint4*)Bp, wr2, d2b, Cb,
                                           st + 2 * 512);

  // act3: GN+SiLU(Cb) + enc1 -> Cp
  act_k<25600, 160, 2, ushort><<<16 * 100, 256, 0, stream>>>(
      Cb, st + 2 * 512, d2gw, d2gb, enc1, Cp);

  // stage 3: conv(Cp) -> Db, stats st3  (WT=32, NG=2: 80 x-y tiles)
  convm_k<160, 160, 32, 2, 10, 64, false, 2, 8>
    <<<dim3(80, 16), 256, 0, stream>>>((const uint4*)Cp, wr3, d3b, Db,
                                       st + 3 * 512);

  // readout: Y = 1x1conv(GN_SiLU(Db)), 2 px/thread
  readout_k<<<(16 * 12800 + 255) / 256, 256, 0, stream>>>(Db, st + 3 * 512,
      d3gw, d3gb, rw, rb, Y);

  feamap_k<<<(16 * 3 * 1600 + 255) / 256, 256, 0, stream>>>(Y, fw, argx);
  final_k<<<(16 * 3 * 25600 + 255) / 256, 256, 0, stream>>>(Y, attn, argx,
      (float*)d_out);
}

// Round 23
// 234.696 us; speedup vs baseline: 1.0897x; 1.0036x over previous
//
#include <hip/hip_runtime.h>

// ---------------------------------------------------------------------------
// SimVP Decoder, round 23: R21 (235.5us, best) + CORRECT ragged WT=32 tiles
// for conv1/conv2.
// R22 post-mortem: WT=40/NG=3 tiles OVERLAPPED (cols 40-47 computed by both
// tiles) -> GN stats double-counted those columns -> absmax 3.4e-2 fail.
// Also 86KB LDS -> 1 block/CU. Now: stages 1/2 use WT=32/NG=2/NTX=3
// (x0=0,32,64; non-overlapping since NG*16==WT; last tile ragged, gated by
// x<WIN). Predicate: ((NG*16==WT)&&(WIN%WT==0)) || ((xb+lx)<WT && x<WIN),
// constexpr-folded per stage. LDS 61.4KB -> 2 blocks/CU (same as stage 3).
// Everything else byte-identical to R21 (passed, absmax 0.0078).
// ---------------------------------------------------------------------------

#define DEVFN static __device__ __forceinline__

typedef short v8s __attribute__((ext_vector_type(8)));
typedef float v4f __attribute__((ext_vector_type(4)));

DEVFN float silu_f(float t) { return t / (1.f + __expf(-t)); }

DEVFN ushort f2bf(float x) {
  union { float f; unsigned u; } t; t.f = x;
  unsigned r = t.u + 0x7FFFu + ((t.u >> 16) & 1u);
  return (ushort)(r >> 16);
}

DEVFN float bf2f(unsigned u) {
  union { unsigned i; float f; } t; t.i = u << 16; return t.f;
}

DEVFN float ldf(float x) { return x; }
DEVFN float ldf(ushort u) { return bf2f(u); }

// ---- fused prep: zero stats + repack all 4 weight tensors -----------------
DEVFN void repack1(const float* __restrict__ src, ushort* __restrict__ dst,
                   int i, int OC) {
  int oc = i / 576, r = i - oc * 576;      // r = ic*9 + tap
  int ic = r / 9, tap = r - ic * 9;
  int kc = tap * 8 + (ic >> 3), j = ic & 7;
  dst[((size_t)kc * OC + oc) * 8 + j] = f2bf(src[i]);
}

__global__ __launch_bounds__(256)
void prep_k(const float* __restrict__ s0, const float* __restrict__ s1,
            const float* __restrict__ s2, const float* __restrict__ s3,
            ushort* __restrict__ d0, ushort* __restrict__ d1,
            ushort* __restrict__ d2, ushort* __restrict__ d3,
            float* __restrict__ st)
{
  int i = blockIdx.x * 256 + threadIdx.x;
  if (i < 2048) st[i] = 0.f;
  int j = i;
  if (j < 147456) { repack1(s0, d0, j, 256); return; }
  j -= 147456;
  if (j < 36864)  { repack1(s1, d1, j, 64);  return; }
  j -= 36864;
  if (j < 147456) { repack1(s2, d2, j, 256); return; }
  j -= 147456;
  if (j < 36864)  { repack1(s3, d3, j, 64);  return; }
}

// ---- fused border zeroing for the 3 padded NHWC buffers -------------------
__global__ __launch_bounds__(256)
void border3_k(ushort* __restrict__ hidP, ushort* __restrict__ Ap,
               ushort* __restrict__ Cp)
{
  int i = blockIdx.x * 256 + threadIdx.x;
  ushort* buf; int HPx, idx;
  if (i < 16 * 42 * 42) { buf = hidP; HPx = 42; idx = i; }
  else if (i < 16 * 42 * 42 + 16 * 82 * 82) {
    buf = Ap; HPx = 82; idx = i - 16 * 42 * 42;
  } else if (i < 16 * 42 * 42 + 16 * 82 * 82 + 16 * 162 * 162) {
    buf = Cp; HPx = 162; idx = i - 16 * 42 * 42 - 16 * 82 * 82;
  } else return;
  int p = idx % (HPx * HPx);
  int y = p / HPx, x = p - y * HPx;
  if (y == 0 || y == HPx - 1 || x == 0 || x == HPx - 1) {
    uint4 z = {0u, 0u, 0u, 0u};
    uint4* dst = (uint4*)(buf + (size_t)idx * 64);
    #pragma unroll
    for (int k = 0; k < 8; ++k) dst[k] = z;
  }
}

// ---- slot-summed GN stats -> (mean, rstd) ---------------------------------
DEVFN void gn_stats(const float* __restrict__ st, int bg, float N,
                    float& mean, float& rstd) {
  float s = 0.f, q = 0.f;
  #pragma unroll
  for (int sl = 0; sl < 8; ++sl) {
    s += st[sl * 64 + bg * 2 + 0];
    q += st[sl * 64 + bg * 2 + 1];
  }
  float m = s / N;
  mean = m;
  rstd = rsqrtf(q / N - m * m + 1e-5f);
}

// ---- act: NCHW (f32 or bf16) -> padded NHWC bf16 via swizzled LDS ---------
// MODE: 0 copy (pad only); 1 GN+SiLU; 2 GN+SiLU + addsrc(f32)
template<int HW_TOT, int WOUT, int MODE, typename T>
__global__ __launch_bounds__(256)
void act_k(const T* __restrict__ in, const float* __restrict__ st,
           const float* __restrict__ gw, const float* __restrict__ gb,
           const float* __restrict__ addsrc, ushort* __restrict__ outP)
{
  constexpr int HOUT = HW_TOT / WOUT;
  constexpr int WP = WOUT + 2, HP = HOUT + 2;
  __shared__ uint4 sT[256 * 8];            // [pixel][slot], slot = cc ^ (pix&7)
  const int tid = threadIdx.x;
  constexpr int NBLK = (HW_TOT + 255) / 256;
  const int b  = blockIdx.x / NBLK;
  const int p0 = (blockIdx.x - b * NBLK) * 256;
  const int px = p0 + tid;

  float mean[2], rstd[2];
  if (MODE >= 1) {
    const float N = 32.f * HW_TOT;
    #pragma unroll
    for (int g = 0; g < 2; ++g) gn_stats(st, b * 2 + g, N, mean[g], rstd[g]);
  }
  if (px < HW_TOT) {
    const T* ip = in + (size_t)b * 64 * HW_TOT + px;
    #pragma unroll 2
    for (int cc = 0; cc < 8; ++cc) {
      unsigned w[4];
      #pragma unroll
      for (int jp = 0; jp < 4; ++jp) {
        float v0, v1;
        #pragma unroll
        for (int h = 0; h < 2; ++h) {
          int c = cc * 8 + jp * 2 + h;
          float v = ldf(ip[(size_t)c * HW_TOT]);
          if (MODE >= 1) {
            v = silu_f((v - mean[c >> 5]) * rstd[c >> 5] * gw[c] + gb[c]);
            if (MODE == 2) v += addsrc[(size_t)(b * 64 + c) * HW_TOT + px];
          }
          if (h == 0) v0 = v; else v1 = v;
        }
        w[jp] = (unsigned)f2bf(v0) | ((unsigned)f2bf(v1) << 16);
      }
      uint4 pk = {w[0], w[1], w[2], w[3]};
      sT[tid * 8 + (cc ^ (tid & 7))] = pk;
    }
  }
  __syncthreads();
  const int o = tid & 7, pr = tid >> 3;
  #pragma unroll
  for (int i = 0; i < 8; ++i) {
    int p = i * 32 + pr;
    int gpx = p0 + p;
    if (gpx < HW_TOT) {
      int y = gpx / WOUT, x = gpx - y * WOUT;
      uint4 val = sT[p * 8 + (o ^ (p & 7))];
      *(uint4*)(outP + (((size_t)(b * HP) + y + 1) * WP + (x + 1)) * 64 + o * 8) = val;
    }
  }
}

// ---- MFMA implicit-GEMM 3x3 conv, single-staged row strip -----------------
// In: padded NHWC bf16. Out: bf16 NCHW, PRE-NORM (stats fused, f32 accs).

#define FE18(M) M(0) M(1) M(2) M(3) M(4) M(5) M(6) M(7) M(8) M(9) M(10) \
                M(11) M(12) M(13) M(14) M(15) M(16) M(17)

#define WDL(t) \
  v8s Wa##t = ((const v8s*)wrep)[(size_t)((t) * 4 + sub) * OCT + ocbase + lx]; \
  v8s Wb##t = ((const v8s*)wrep)[(size_t)((t) * 4 + sub) * OCT + ocbase + 16 + lx];

// step t: tap = t>>1 (dy=t/6, dx=(t>>1)%3), icc-half = t&1
#define KST(t) { \
    const int col_ = lx + (((t) >> 1) % 3); \
    v8s b_ = __builtin_bit_cast(v8s, sQ[((rbase + wrow + (t) / 6) * LWS + xb + col_) * 8 + \
                                        (((((t) & 1) * 4 + sub)) ^ ((xb + col_) & 7))]); \
    a0 = __builtin_amdgcn_mfma_f32_16x16x32_bf16(Wa##t, b_, a0, 0, 0, 0); \
    a1 = __builtin_amdgcn_mfma_f32_16x16x32_bf16(Wb##t, b_, a1, 0, 0, 0); }

template<int HIN, int WIN, int WT, int NG, int RPB, int OCT, bool PSF,
         int WEU_MIN, int WEU_MAX>
__global__
__attribute__((amdgpu_flat_work_group_size(256, 256),
               amdgpu_waves_per_eu(WEU_MIN, WEU_MAX)))
void convm_k(const uint4* __restrict__ inP, const ushort* __restrict__ wrep,
             const float* __restrict__ bias, ushort* __restrict__ out,
             float* __restrict__ stp)
{
  constexpr int HP = HIN + 2, WP = WIN + 2;
  constexpr int LH = RPB + 2, LW = WT + 2;
  constexpr int NOCB = OCT / 64;
  constexpr int LRD = (NG * 16 + 2 > LW) ? (NG * 16 + 2) : LW;
  constexpr int LWS = (LRD + 7) & ~7;      // multiple of 8: (pix&7)==(col&7)
  constexpr int NCHUNK = LH * LWS * 8;
  static_assert(NCHUNK % 256 == 0, "staging must tile evenly");
  constexpr int STK = NCHUNK / 256;
  // full-coverage tiles never overlap; ragged tiles are gated per-column
  constexpr bool FULLW = (NG * 16 == WT) && (WIN % WT == 0);
  __shared__ uint4 sQ[NCHUNK];
  __shared__ float red[4][2];

  const int tid  = threadIdx.x;
  const int lane = tid & 63;
  const int wave = tid >> 6;
  const int sub  = lane >> 4;
  const int lx   = lane & 15;
  const int wrow = wave >> 1;              // row within pair
  const int b    = blockIdx.y / NOCB;
  const int ocb  = blockIdx.y - b * NOCB;
  constexpr int NTX = (WIN + WT - 1) / WT;
  const int tx    = blockIdx.x % NTX;
  const int ych   = blockIdx.x / NTX;
  const int x0    = tx * WT;
  const int ybase = ych * RPB;
  const int ocbase = ocb * 64 + (wave & 1) * 32;

  // staging FIRST: batched loads -> LDS (staging regs die here).
  // Ragged-tile overread stays inside d_ws and feeds only discarded lanes.
  const uint4* gbase = inP + ((size_t)(b * HP + ybase) * WP + x0) * 8;
  {
    uint4 stg[STK];
    #pragma unroll
    for (int k = 0; k < STK; ++k) {
      int q = tid + k * 256;
      int p = q >> 3, cc = q & 7;
      int r = p / LWS, cx = p - r * LWS;
      stg[k] = gbase[((size_t)r * WP + cx) * 8 + cc];
    }
    #pragma unroll
    for (int k = 0; k < STK; ++k) {
      int q = tid + k * 256;
      int p = q >> 3, cc = q & 7;
      int cx = p - (p / LWS) * LWS;
      sQ[p * 8 + (cc ^ (cx & 7))] = stg[k];
    }
  }

  // weights AFTER staging (overlap LDS-write drain, pre-barrier)
  FE18(WDL)

  const v4f bi0 = *(const v4f*)&bias[ocbase + sub * 4];
  const v4f bi1 = *(const v4f*)&bias[ocbase + 16 + sub * 4];

  __syncthreads();

  float sA = 0.f, qA = 0.f;

  for (int it = 0; it < RPB / 2; ++it) {
    const int rbase = it * 2;
    const int y = ybase + rbase + wrow;
    for (int xg = 0; xg < NG; ++xg) {
      const int xb = xg * 16;
      v4f a0 = bi0, a1 = bi1;
      FE18(KST)
      const int x = x0 + xb + lx;
      // own-tile columns only (no overlap -> no stats double-count)
      const bool valid = FULLW || ((xb + lx) < WT && x < WIN);
      if (valid) {
        #pragma unroll
        for (int s = 0; s < 2; ++s) {
          const v4f a = s ? a1 : a0;
          if (!PSF) {
            #pragma unroll
            for (int j = 0; j < 4; ++j) {
              int oc = ocbase + s * 16 + sub * 4 + j;
              out[((size_t)(b * OCT + oc) * HIN + y) * WIN + x] = f2bf(a[j]);
            }
          } else {
            // lane owns the full 2x2 quad of plane c
            const int c = (ocbase + s * 16 + sub * 4) >> 2;
            unsigned top = (unsigned)f2bf(a[0]) | ((unsigned)f2bf(a[1]) << 16);
            unsigned bot = (unsigned)f2bf(a[2]) | ((unsigned)f2bf(a[3]) << 16);
            const size_t qb =
              ((size_t)(b * 64 + c) * (2 * HIN) + 2 * y) * (2 * WIN) + 2 * x;
            *(unsigned*)(out + qb) = top;
            *(unsigned*)(out + qb + 2 * WIN) = bot;
          }
          #pragma unroll
          for (int j = 0; j < 4; ++j) { sA += a[j]; qA += a[j] * a[j]; }
        }
      }
    }
  }

  // GroupNorm stats (f32 accumulators, exact)
  #pragma unroll
  for (int o = 32; o >= 1; o >>= 1) {
    sA += __shfl_down(sA, o);
    qA += __shfl_down(qA, o);
  }
  if (lane == 0) { red[wave][0] = sA; red[wave][1] = qA; }
  __syncthreads();
  if (tid == 0) {
    float* basep = stp + ((blockIdx.x ^ blockIdx.y) & 7) * 64;
    if (PSF) {
      int g = ocb >> 1;
      atomicAdd(&basep[(b * 2 + g) * 2 + 0],
                red[0][0] + red[1][0] + red[2][0] + red[3][0]);
      atomicAdd(&basep[(b * 2 + g) * 2 + 1],
                red[0][1] + red[1][1] + red[2][1] + red[3][1]);
    } else {
      atomicAdd(&basep[(b * 2 + 0) * 2 + 0], red[0][0] + red[2][0]);
      atomicAdd(&basep[(b * 2 + 0) * 2 + 1], red[0][1] + red[2][1]);
      atomicAdd(&basep[(b * 2 + 1) * 2 + 0], red[1][0] + red[3][0]);
      atomicAdd(&basep[(b * 2 + 1) * 2 + 1], red[1][1] + red[3][1]);
    }
  }
}

// ---- readout, 2 pixels/thread (u32 bf16x2 plane loads) --------------------
__global__ __launch_bounds__(256)
void readout_k(const ushort* __restrict__ D, const float* __restrict__ st,
               const float* __restrict__ gw, const float* __restrict__ gb,
               const float* __restrict__ rw, const float* __restrict__ rb,
               float* __restrict__ Y)
{
  int idx = blockIdx.x * 256 + threadIdx.x;
  if (idx >= 16 * 12800) return;
  int b = idx / 12800, pp = (idx - b * 12800) * 2;
  const float N = 32.f * 25600.f;
  float mean[2], rstd[2];
  #pragma unroll
  for (int g = 0; g < 2; ++g) gn_stats(st, b * 2 + g, N, mean[g], rstd[g]);
  float a0 = rb[0], a1 = rb[1], a2 = rb[2];
  float c0a = rb[0], c1a = rb[1], c2a = rb[2];
  const ushort* dp = D + (size_t)(b * 64) * 25600 + pp;
  #pragma unroll 4
  for (int c = 0; c < 64; ++c) {
    unsigned w = *(const unsigned*)(dp + (size_t)c * 25600);
    float m = mean[c >> 5], rs = rstd[c >> 5];
    float v0 = silu_f((bf2f(w & 0xffffu) - m) * rs * gw[c] + gb[c]);
    float v1 = silu_f((bf2f(w >> 16) - m) * rs * gw[c] + gb[c]);
    a0  = fmaf(v0, rw[c], a0);        c0a = fmaf(v1, rw[c], c0a);
    a1  = fmaf(v0, rw[64 + c], a1);   c1a = fmaf(v1, rw[64 + c], c1a);
    a2  = fmaf(v0, rw[128 + c], a2);  c2a = fmaf(v1, rw[128 + c], c2a);
  }
  float2* y0 = (float2*)&Y[(size_t)(b * 3 + 0) * 25600 + pp];
  float2* y1 = (float2*)&Y[(size_t)(b * 3 + 1) * 25600 + pp];
  float2* y2 = (float2*)&Y[(size_t)(b * 3 + 2) * 25600 + pp];
  *y0 = make_float2(a0, c0a);
  *y1 = make_float2(a1, c1a);
  *y2 = make_float2(a2, c2a);
}

// ---- feamap: argx = conv(Y, fw, stride 4)/16, first 3 channels ------------
__global__ void feamap_k(const float* __restrict__ Y, const float* __restrict__ fw,
                         float* __restrict__ argx)
{
  int idx = blockIdx.x * 256 + threadIdx.x;
  if (idx >= 16 * 3 * 1600) return;
  int b  = idx / (3 * 1600);
  int o  = (idx / 1600) % 3;
  int ij = idx % 1600;
  int i = ij / 40, j = ij - i * 40;
  float s = 0.f;
  #pragma unroll
  for (int c = 0; c < 3; ++c)
    #pragma unroll
    for (int u = 0; u < 4; ++u)
      #pragma unroll
      for (int v = 0; v < 4; ++v)
        s += Y[((size_t)(b * 3 + c) * 160 + (4 * i + u)) * 160 + (4 * j + v)]
             * fw[((o * 3 + c) * 4 + u) * 4 + v];
  argx[idx] = s * (1.f / 16.f);
}

// ---- final: nz folded in (count nonzeros of the attn row we already read) -
__global__ void final_k(const float* __restrict__ Y, const float* __restrict__ attn,
                        const float* __restrict__ argx, float* __restrict__ out)
{
  int idx = blockIdx.x * 256 + threadIdx.x;
  if (idx >= 16 * 3 * 25600) return;
  int bc  = idx / 25600;
  int pix = idx - bc * 25600;
  int y = pix / 160, x = pix - y * 160;
  int l  = (y / 10) * 16 + (x / 10);
  int pi = y % 10,  pj = x % 10;
  const float* ar = attn + ((size_t)bc * 256 + l) * 16;
  const float* ax = argx + (size_t)bc * 1600;
  float corr = 0.f;
  int cnt = 0;
  #pragma unroll
  for (int k = 0; k < 16; ++k) {
    float av = ar[k];
    cnt += (av != 0.f);
    corr += av * ax[((k >> 2) * 10 + pi) * 40 + ((k & 3) * 10 + pj)];
  }
  float inv = 1.f / ((float)cnt + 1e-5f);
  float yv = Y[idx];
  out[idx] = yv * (1.f + corr * inv);
}

// ---------------------------------------------------------------------------
extern "C" void kernel_launch(void* const* d_in, const int* in_sizes, int n_in,
                              void* d_out, int out_size, void* d_ws, size_t ws_size,
                              hipStream_t stream)
{
  const float* attn = (const float*)d_in[0];
  const float* hid  = (const float*)d_in[1];
  const float* enc1 = (const float*)d_in[2];
  const float* d0w  = (const float*)d_in[3];
  const float* d0b  = (const float*)d_in[4];
  const float* d0gw = (const float*)d_in[5];
  const float* d0gb = (const float*)d_in[6];
  const float* d1w  = (const float*)d_in[7];
  const float* d1b  = (const float*)d_in[8];
  const float* d1gw = (const float*)d_in[9];
  const float* d1gb = (const float*)d_in[10];
  const float* d2w  = (const float*)d_in[11];
  const float* d2b  = (const float*)d_in[12];
  const float* d2gw = (const float*)d_in[13];
  const float* d2gb = (const float*)d_in[14];
  const float* d3w  = (const float*)d_in[15];
  const float* d3b  = (const float*)d_in[16];
  const float* d3gw = (const float*)d_in[17];
  const float* d3gb = (const float*)d_in[18];
  const float* rw   = (const float*)d_in[19];
  const float* rb   = (const float*)d_in[20];
  const float* fw   = (const float*)d_in[21];

  float* ws = (float*)d_ws;
  size_t o = 0;
  float* bufA  = ws + o; o += (size_t)16 * 64 * 80 * 80;       // A/Bb (bf16) + Y/argx (f32)
  float* bufAp = ws + o; o += (size_t)16 * 82 * 82 * 64 / 2;   // Ap / Bp  (NHWC bf16)
  float* bufC  = ws + o; o += (size_t)16 * 64 * 160 * 160 / 2; // Cb / Db (NCHW bf16)
  float* bufCp = ws + o; o += (size_t)16 * 162 * 162 * 64 / 2; // Cp (NHWC bf16)
  float* hidPf = ws + o; o += (size_t)16 * 42 * 42 * 64 / 2;   // hidP
  float* st    = ws + o; o += 4 * 512;                         // slotted stats
  float* w0f   = ws + o; o += (size_t)72 * 256 * 8 / 2;
  float* w1f   = ws + o; o += (size_t)72 * 64 * 8 / 2;
  float* w2f   = ws + o; o += (size_t)72 * 256 * 8 / 2;
  float* w3f   = ws + o; o += (size_t)72 * 64 * 8 / 2;

  ushort* A    = (ushort*)bufA;            // bf16 NCHW [16,64,80,80]
  ushort* Bb   = (ushort*)bufA;            // aliases A (A dead after act1)
  ushort* Ap   = (ushort*)bufAp;
  ushort* Bp   = (ushort*)bufAp;
  ushort* Cb   = (ushort*)bufC;
  ushort* Db   = (ushort*)bufC;
  ushort* Cp   = (ushort*)bufCp;
  ushort* hidP = (ushort*)hidPf;
  float*  Y    = bufA;                     // Bb dead after act2
  float*  argx = bufA + (size_t)16 * 3 * 25600;
  ushort* wr0  = (ushort*)w0f;
  ushort* wr1  = (ushort*)w1f;
  ushort* wr2  = (ushort*)w2f;
  ushort* wr3  = (ushort*)w3f;

  // fused prep: zero stats + repack 4 weight tensors (368640 elems)
  prep_k<<<(368640 + 255) / 256, 256, 0, stream>>>(d0w, d1w, d2w, d3w,
                                                   wr0, wr1, wr2, wr3, st);

  // fused borders for hidP / Ap(+Bp) / Cp
  border3_k<<<(16 * (42 * 42 + 82 * 82 + 162 * 162) + 255) / 256, 256, 0,
              stream>>>(hidP, Ap, Cp);

  // pad hid -> hidP (NHWC bf16)
  act_k<1600, 40, 0, float><<<16 * 7, 256, 0, stream>>>(
      hid, nullptr, nullptr, nullptr, nullptr, hidP);

  // stage 0: conv(hidP)+PS -> A (bf16 NCHW, pre-norm), stats st0
  convm_k<40, 40, 40, 3, 10, 256, true, 1, 1>
    <<<dim3(4, 16 * 4), 256, 0, stream>>>((const uint4*)hidP, wr0, d0b, A,
                                          st + 0 * 512);

  // act1: GN+SiLU(A) -> Ap (NHWC)
  act_k<6400, 80, 1, ushort><<<16 * 25, 256, 0, stream>>>(
      A, st + 0 * 512, d0gw, d0gb, nullptr, Ap);

  // stage 1: conv(Ap) -> Bb, stats st1  (WT=32 NG=2, NTX=3 ragged)
  convm_k<80, 80, 32, 2, 10, 64, false, 2, 8>
    <<<dim3(24, 16), 256, 0, stream>>>((const uint4*)Ap, wr1, d1b, Bb,
                                       st + 1 * 512);

  // act2: GN+SiLU(Bb) -> Bp
  act_k<6400, 80, 1, ushort><<<16 * 25, 256, 0, stream>>>(
      Bb, st + 1 * 512, d1gw, d1gb, nullptr, Bp);

  // stage 2: conv(Bp)+PS -> Cb, stats st2  (WT=32 NG=2, NTX=3 ragged)
  convm_k<80, 80, 32, 2, 10, 256, true, 2, 8>
    <<<dim3(24, 16 * 4), 256, 0, stream>>>((const uint4*)Bp, wr2, d2b, Cb,
                                           st + 2 * 512);

  // act3: GN+SiLU(Cb) + enc1 -> Cp
  act_k<25600, 160, 2, ushort><<<16 * 100, 256, 0, stream>>>(
      Cb, st + 2 * 512, d2gw, d2gb, enc1, Cp);

  // stage 3: conv(Cp) -> Db, stats st3  (WT=32, NG=2: 80 x-y tiles)
  convm_k<160, 160, 32, 2, 10, 64, false, 2, 8>
    <<<dim3(80, 16), 256, 0, stream>>>((const uint4*)Cp, wr3, d3b, Db,
                                       st + 3 * 512);

  // readout: Y = 1x1conv(GN_SiLU(Db)), 2 px/thread
  readout_k<<<(16 * 12800 + 255) / 256, 256, 0, stream>>>(Db, st + 3 * 512,
      d3gw, d3gb, rw, rb, Y);

  feamap_k<<<(16 * 3 * 1600 + 255) / 256, 256, 0, stream>>>(Y, fw, argx);
  final_k<<<(16 * 3 * 25600 + 255) / 256, 256, 0, stream>>>(Y, attn, argx,
      (float*)d_out);
}